// Round 4
// baseline (475.759 us; speedup 1.0000x reference)
//
#include <hip/hip_runtime.h>
#include <hip/hip_bf16.h>

typedef unsigned short ushort_t;
typedef __attribute__((ext_vector_type(8))) short short8;   // 8 bf16 (4 VGPRs) - MFMA A/B frag
typedef __attribute__((ext_vector_type(4))) short short4v;  // 4 bf16 (8B store)
typedef __attribute__((ext_vector_type(4))) float f32x4;    // MFMA C/D frag

#define DEVI static __device__ __forceinline__

DEVI float bf2f(ushort_t u) { union { unsigned int i; float f; } v; v.i = ((unsigned int)u) << 16; return v.f; }
DEVI ushort_t f2bf(float f) {
  union { float f; unsigned int i; } v; v.f = f;
  unsigned int x = v.i;
  return (ushort_t)((x + 0x7fffu + ((x >> 16) & 1u)) >> 16);   // round-to-nearest-even
}

// ---------------- problem constants ----------------
// B=64, N=400, F_IN=240, C=128, NL=2880 ; M = 25600
#define SZ_XB   6144000   // 25600*240
#define SZ_AB    160000   // 400*400
#define SZ_WV1   61440    // 256*240  ([W1|V1]^T)
#define SZ_WV2   32768    // 256*128  ([W2|V2]^T)
#define SZ_WDT   368640   // 2880*128 (wd^T)
#define CVT_TOTAL (SZ_XB + SZ_AB + SZ_WV1 + SZ_WV2 + SZ_WDT)  // 6,766,848
#define WS_NEEDED 33194496ull
#define OUT_TOTAL 73728000   // 25600*2880

// Fallback: if workspace is too small we still must enqueue work (graph capture
// of an empty stream can fail). Zero d_out -> clean absmax failure as signal.
__global__ void fallback_zero(float* __restrict__ out) {
  long t = (long)blockIdx.x * blockDim.x + threadIdx.x;
  if (t < OUT_TOTAL) out[t] = 0.f;
}

// One fused f32->bf16 convert + weight-transpose kernel.
__global__ void convert_kernel(const float* __restrict__ x, const float* __restrict__ a,
                               const float* __restrict__ w1, const float* __restrict__ v1,
                               const float* __restrict__ w2, const float* __restrict__ v2,
                               const float* __restrict__ wd,
                               ushort_t* __restrict__ xb, ushort_t* __restrict__ ab,
                               ushort_t* __restrict__ wv1t, ushort_t* __restrict__ wv2t,
                               ushort_t* __restrict__ wdt) {
  long t = (long)blockIdx.x * blockDim.x + threadIdx.x;
  if (t >= CVT_TOTAL) return;
  if (t < SZ_XB) { xb[t] = f2bf(x[t]); return; }
  t -= SZ_XB;
  if (t < SZ_AB) { ab[t] = f2bf(a[t]); return; }
  t -= SZ_AB;
  if (t < SZ_WV1) {                      // wv1t[n][k] = (n<128 ? w1 : v1)[k][n%128]
    int n = (int)(t / 240), k = (int)(t % 240);
    float v = (n < 128) ? w1[k * 128 + n] : v1[k * 128 + (n - 128)];
    wv1t[t] = f2bf(v); return;
  }
  t -= SZ_WV1;
  if (t < SZ_WV2) {
    int n = (int)(t / 128), k = (int)(t % 128);
    float v = (n < 128) ? w2[k * 128 + n] : v2[k * 128 + (n - 128)];
    wv2t[t] = f2bf(v); return;
  }
  t -= SZ_WV2;
  {
    int n = (int)(t / 128), k = (int)(t % 128);
    wdt[t] = f2bf(wd[k * 2880 + n]);     // wdt[n][k] = wd[k][n]
  }
}

// ---------------- unified MFMA GEMM ----------------
// C[M,N] = A[M,K] @ B[K,N], B given transposed (Bt[N][K]).
// EPI 0: store C^T bf16 into Ct[ldct-major]  (Ct[col][row], 4 contiguous bf16/lane)
// EPI 1: AMIX: h = relu(C + S + bias), S = St[col*ldbt + boff + row]; store h bf16
//        row-major [bz*M + row][N]; batched over blockIdx.z (A shared, Bt offset boff)
// EPI 2: dense: Out[row][col] = C + bias[col], f32 row-major, ld = N
#define BM 128
#define BN 128
#define BK 32
#define LDSS 40   // padded LDS row stride (elems): 80B rows -> 2-way (free) bank aliasing

template <int EPI>
__global__ __launch_bounds__(256) void gemm_kernel(
    const ushort_t* __restrict__ A, int lda,
    const ushort_t* __restrict__ Bt, int ldbt, int bt_boff,
    int M, int N, int K,
    ushort_t* __restrict__ Ct, int ldct,
    const ushort_t* __restrict__ St,
    const float* __restrict__ bias,
    ushort_t* __restrict__ H,
    float* __restrict__ Out) {
  __shared__ ushort_t As[BM][LDSS];
  __shared__ ushort_t Bs[BN][LDSS];

  const int tid = threadIdx.x;
  const int lane = tid & 63;
  const int wave = tid >> 6;
  const int wr = wave >> 1, wc = wave & 1;
  const int bz = blockIdx.z;
  const int gm = blockIdx.x * BM;
  const int gn = blockIdx.y * BN;
  const int boff = bz * bt_boff;

  f32x4 acc[4][4];
#pragma unroll
  for (int m = 0; m < 4; ++m)
#pragma unroll
    for (int n = 0; n < 4; ++n) acc[m][n] = (f32x4){0.f, 0.f, 0.f, 0.f};

  // staging: 128 rows x 32 k per tile; thread t covers row=t>>1, 16-elem half kp
  const int srow = tid >> 1;
  const int skp = (tid & 1) * 16;
  int arow = gm + srow; if (arow > M - 1) arow = M - 1;   // clamp: dead rows only
  int brow = gn + srow; if (brow > N - 1) brow = N - 1;
  const ushort_t* aptr = A + (long)arow * lda + skp;
  const ushort_t* bptr = Bt + (long)brow * ldbt + boff + skp;

  const int cl = lane & 15;
  const int k8 = (lane >> 4) * 8;

  for (int k0 = 0; k0 < K; k0 += BK) {
    uint4 a0 = {0, 0, 0, 0}, a1 = {0, 0, 0, 0};
    uint4 b0 = {0, 0, 0, 0}, b1 = {0, 0, 0, 0};
    if (k0 + skp < K) {  // K % 16 == 0 for all call sites -> chunk fully in/out
      a0 = *(const uint4*)(aptr + k0);
      a1 = *(const uint4*)(aptr + k0 + 8);
      b0 = *(const uint4*)(bptr + k0);
      b1 = *(const uint4*)(bptr + k0 + 8);
    }
    *(uint4*)&As[srow][skp] = a0;
    *(uint4*)&As[srow][skp + 8] = a1;
    *(uint4*)&Bs[srow][skp] = b0;
    *(uint4*)&Bs[srow][skp + 8] = b1;
    __syncthreads();

    short8 af[4], bf[4];
#pragma unroll
    for (int m = 0; m < 4; ++m) af[m] = *(const short8*)&As[wr * 64 + m * 16 + cl][k8];
#pragma unroll
    for (int n = 0; n < 4; ++n) bf[n] = *(const short8*)&Bs[wc * 64 + n * 16 + cl][k8];
#pragma unroll
    for (int m = 0; m < 4; ++m)
#pragma unroll
      for (int n = 0; n < 4; ++n)
        acc[m][n] = __builtin_amdgcn_mfma_f32_16x16x32_bf16(af[m], bf[n], acc[m][n], 0, 0, 0);
    __syncthreads();
  }

  // epilogue: C/D frag layout col = lane&15, row = (lane>>4)*4 + j  [m89/m91-verified]
  const int rq = (lane >> 4) * 4;
#pragma unroll
  for (int m = 0; m < 4; ++m) {
    const int row = gm + wr * 64 + m * 16 + rq;
#pragma unroll
    for (int n = 0; n < 4; ++n) {
      const int col = gn + wc * 64 + n * 16 + cl;
      if constexpr (EPI == 0) {
        if (row < M && col < N) {
          short4v pk;
          pk[0] = (short)f2bf(acc[m][n][0]);
          pk[1] = (short)f2bf(acc[m][n][1]);
          pk[2] = (short)f2bf(acc[m][n][2]);
          pk[3] = (short)f2bf(acc[m][n][3]);
          *(short4v*)(Ct + (long)col * ldct + row) = pk;   // C^T: 4 contiguous bf16
        }
      } else if constexpr (EPI == 1) {
        if (row < M && col < N) {
          const float bv = bias[col];
          const ushort_t* sp = St + (long)col * ldbt + boff + row;  // S^T, contiguous in row
          ushort_t* hp = H + ((long)bz * M + row) * N + col;
          float v0 = acc[m][n][0] + bf2f(sp[0]) + bv; if (v0 < 0.f) v0 = 0.f;
          float v1 = acc[m][n][1] + bf2f(sp[1]) + bv; if (v1 < 0.f) v1 = 0.f;
          float v2 = acc[m][n][2] + bf2f(sp[2]) + bv; if (v2 < 0.f) v2 = 0.f;
          float v3 = acc[m][n][3] + bf2f(sp[3]) + bv; if (v3 < 0.f) v3 = 0.f;
          hp[0] = f2bf(v0); hp[N] = f2bf(v1); hp[2 * N] = f2bf(v2); hp[3 * N] = f2bf(v3);
        }
      } else {
        if (col < N) {
          const float bv = bias[col];
          float* op = Out + (long)row * N + col;
          op[0] = acc[m][n][0] + bv;
          op[(long)N] = acc[m][n][1] + bv;
          op[2L * N] = acc[m][n][2] + bv;
          op[3L * N] = acc[m][n][3] + bv;
        }
      }
    }
  }
}

// ---------------- launch ----------------
// ws layout (bytes):
//   xb    @ 0          12,288,000
//   ab    @ 12288000      320,000
//   wv1t  @ 12608000      122,880
//   wv2t  @ 12730880       65,536
//   wdt   @ 12796416      737,280
//   TSt   @ 13533696   13,107,200   (256 x 25600 bf16, transposed TS)
//   h     @ 26640896    6,553,600   (25600 x 128 bf16)
extern "C" void kernel_launch(void* const* d_in, const int* in_sizes, int n_in,
                              void* d_out, int out_size, void* d_ws, size_t ws_size,
                              hipStream_t stream) {
  float* out = (float*)d_out;
  if (ws_size < WS_NEEDED) {   // defensive: enqueue real work, fail correctness cleanly
    fallback_zero<<<(OUT_TOTAL + 255) / 256, 256, 0, stream>>>(out);
    return;
  }

  const float* x  = (const float*)d_in[0];
  const float* a  = (const float*)d_in[1];
  const float* w1 = (const float*)d_in[2];
  const float* v1 = (const float*)d_in[3];
  const float* b1 = (const float*)d_in[4];
  const float* w2 = (const float*)d_in[5];
  const float* v2 = (const float*)d_in[6];
  const float* b2 = (const float*)d_in[7];
  const float* wd = (const float*)d_in[8];
  const float* bd = (const float*)d_in[9];

  char* ws = (char*)d_ws;
  ushort_t* xb   = (ushort_t*)(ws);
  ushort_t* ab   = (ushort_t*)(ws + 12288000);
  ushort_t* wv1t = (ushort_t*)(ws + 12608000);
  ushort_t* wv2t = (ushort_t*)(ws + 12730880);
  ushort_t* wdt  = (ushort_t*)(ws + 12796416);
  ushort_t* TSt  = (ushort_t*)(ws + 13533696);
  ushort_t* h    = (ushort_t*)(ws + 26640896);

  convert_kernel<<<(CVT_TOTAL + 255) / 256, 256, 0, stream>>>(x, a, w1, v1, w2, v2, wd,
                                                              xb, ab, wv1t, wv2t, wdt);

  // layer 1: TS1^T = ( x @ [W1|V1] )^T   M=25600 N=256 K=240
  gemm_kernel<0><<<dim3(200, 2, 1), 256, 0, stream>>>(xb, 240, wv1t, 240, 0,
                                                      25600, 256, 240,
                                                      TSt, 25600, nullptr, nullptr, nullptr, nullptr);
  // h1 = relu(A @ T1 + S1 + b1)   batched: 64 x (M=400 N=128 K=400)
  gemm_kernel<1><<<dim3(4, 1, 64), 256, 0, stream>>>(ab, 400, TSt, 25600, 400,
                                                     400, 128, 400,
                                                     nullptr, 0, TSt + 128L * 25600, b1, h, nullptr);
  // layer 2
  gemm_kernel<0><<<dim3(200, 2, 1), 256, 0, stream>>>(h, 128, wv2t, 128, 0,
                                                      25600, 256, 128,
                                                      TSt, 25600, nullptr, nullptr, nullptr, nullptr);
  gemm_kernel<1><<<dim3(4, 1, 64), 256, 0, stream>>>(ab, 400, TSt, 25600, 400,
                                                     400, 128, 400,
                                                     nullptr, 0, TSt + 128L * 25600, b2, h, nullptr);
  // layer 3 (conv2 reused)
  gemm_kernel<0><<<dim3(200, 2, 1), 256, 0, stream>>>(h, 128, wv2t, 128, 0,
                                                      25600, 256, 128,
                                                      TSt, 25600, nullptr, nullptr, nullptr, nullptr);
  gemm_kernel<1><<<dim3(4, 1, 64), 256, 0, stream>>>(ab, 400, TSt, 25600, 400,
                                                     400, 128, 400,
                                                     nullptr, 0, TSt + 128L * 25600, b2, h, nullptr);
  // dense head: out = h3 @ wd + bd   M=25600 N=2880 K=128, f32 out
  gemm_kernel<2><<<dim3(200, 23, 1), 256, 0, stream>>>(h, 128, wdt, 128, 0,
                                                       25600, 2880, 128,
                                                       nullptr, 0, nullptr, bd, nullptr, out);
}